// Round 3
// baseline (109.966 us; speedup 1.0000x reference)
//
#include <hip/hip_runtime.h>
#include <hip/hip_bf16.h>

#define BATCH 8192
#define DIM   512
#define NCL   1024
#define ROWS  32
#define BK    32
#define NCH   (DIM / BK)   // 16 chunks of 32 along D

typedef __bf16 bf16x8 __attribute__((ext_vector_type(8)));
typedef float  f32x4  __attribute__((ext_vector_type(4)));

__device__ __forceinline__ unsigned short f2bf(float f) {
  union { float f; unsigned u; } v; v.f = f;
  unsigned r = v.u + 0x7fffu + ((v.u >> 16) & 1u);   // RNE, inputs finite
  return (unsigned short)(r >> 16);
}
__device__ __forceinline__ unsigned pk(float a, float b) {
  return (unsigned)f2bf(a) | ((unsigned)f2bf(b) << 16);
}

// weight [1024][512] fp32 -> chunk-major bf16 wck[16][1024][32] (unpadded: B-frag
// reads from global are 64B-line exact), plus wsq[1024]. One wave per cluster row.
__global__ __launch_bounds__(256) void prep_w(const float* __restrict__ w,
                                              __hip_bfloat16* __restrict__ wck,
                                              float* __restrict__ wsq) {
  int k    = blockIdx.x * 4 + (threadIdx.x >> 6);
  int lane = threadIdx.x & 63;
  const float4* wrow = (const float4*)(w + (size_t)k * DIM);
  float4 a = wrow[lane * 2 + 0];
  float4 b = wrow[lane * 2 + 1];
  float s = a.x*a.x + a.y*a.y + a.z*a.z + a.w*a.w
          + b.x*b.x + b.y*b.y + b.z*b.z + b.w*b.w;
  #pragma unroll
  for (int m = 32; m >= 1; m >>= 1) s += __shfl_xor(s, m, 64);
  if (lane == 0) wsq[k] = s;
  int c = lane >> 2;          // this lane's 8 elems (d0 = lane*8) live in chunk c
  int j = (lane & 3) * 8;     // offset within chunk
  uint4 p = { pk(a.x, a.y), pk(a.z, a.w), pk(b.x, b.y), pk(b.z, b.w) };
  *(uint4*)(wck + ((size_t)c * NCL + k) * BK + j) = p;   // 16B aligned
}

// Fused: 32 rows x 1024 cols per block, 8 waves (each: 128-col strip, 2x8 16x16 tiles).
// A-fragments pre-swizzled in LDS (conflict-free ds_read_b128); B-fragments read
// DIRECTLY from L2-resident wck, register-double-buffered -> zero K-loop barriers.
__global__ __launch_bounds__(512) void fused(const float* __restrict__ x,
                                             const __hip_bfloat16* __restrict__ wck,
                                             const float* __restrict__ wsq,
                                             float* __restrict__ out) {
  // xs2[c][rt][lane*8 + j]: MFMA A-fragment layout, tile (c, rt) = 512 elems (1 KB)
  __shared__ __align__(16) __hip_bfloat16 xs2[NCH * 2 * 512];   // 32 KB
  __shared__ float wsq_s[NCL];                                  // 4 KB
  __shared__ float xsq_s[ROWS];
  __shared__ float red[ROWS][9];                                // 8 waves + pad
  __shared__ float rowtot[ROWS];

  const int tid = threadIdx.x;
  const int r0  = blockIdx.x * ROWS;

  const int wave = tid >> 6;
  const int lane = tid & 63;
  const int m16  = lane & 15;
  const int quad = lane >> 4;
  const int col0 = wave * 128;

  // ---- prologue: issue chunk-0 B-fragment loads NOW (L2 latency hides under
  //      the x-staging + barrier below; no sync needed, wck from prior kernel) ----
  bf16x8 bcur[8];
  {
    const __hip_bfloat16* wp0 = wck + (size_t)(col0 + m16) * BK + quad * 8;
    #pragma unroll
    for (int ct = 0; ct < 8; ++ct)
      bcur[ct] = *(const bf16x8*)(wp0 + ct * (16 * BK));   // 1KB/instr, L2
  }

  // ---- stage x fp32->bf16 into A-frag layout + per-row sum of squares ----
  {
    int row = tid >> 4;          // 0..31
    int seg = tid & 15;          // = chunk c: this thread owns 32 consecutive d
    int rt  = row >> 4, m = row & 15;
    const float4* src = (const float4*)(x + (size_t)(r0 + row) * DIM + seg * BK);
    __hip_bfloat16* dst = xs2 + (seg * 2 + rt) * 512 + m * 8;
    float ss = 0.f;
    #pragma unroll
    for (int i = 0; i < 8; ++i) {       // quad = i>>1, half = i&1
      float4 v = src[i];
      ss += v.x*v.x + v.y*v.y + v.z*v.z + v.w*v.w;
      uint2 p = { pk(v.x, v.y), pk(v.z, v.w) };
      *(uint2*)(dst + (i >> 1) * 128 + (i & 1) * 4) = p;
    }
    ss += __shfl_xor(ss, 1, 64);
    ss += __shfl_xor(ss, 2, 64);
    ss += __shfl_xor(ss, 4, 64);
    ss += __shfl_xor(ss, 8, 64);
    if (seg == 0) xsq_s[row] = ss;
    wsq_s[tid]       = wsq[tid];
    wsq_s[tid + 512] = wsq[tid + 512];
  }

  f32x4 acc[2][8];
  #pragma unroll
  for (int rt = 0; rt < 2; ++rt)
    #pragma unroll
    for (int ct = 0; ct < 8; ++ct)
      acc[rt][ct] = (f32x4){0.f, 0.f, 0.f, 0.f};

  __syncthreads();   // xs2 / wsq_s visible; the ONLY barrier before the epilogue

  bf16x8 a0 = *(const bf16x8*)(xs2 + 0 * 512 + lane * 8);
  bf16x8 a1 = *(const bf16x8*)(xs2 + 1 * 512 + lane * 8);

  // ---- K-loop: register double-buffer, prefetch c+1 while MFMA on c ----
  #pragma unroll
  for (int c = 0; c < NCH; ++c) {
    bf16x8 bnx[8], na0, na1;
    if (c + 1 < NCH) {
      const __hip_bfloat16* wp = wck + ((size_t)(c + 1) * NCL + col0 + m16) * BK + quad * 8;
      #pragma unroll
      for (int ct = 0; ct < 8; ++ct)
        bnx[ct] = *(const bf16x8*)(wp + ct * (16 * BK));
      na0 = *(const bf16x8*)(xs2 + ((c + 1) * 2 + 0) * 512 + lane * 8);
      na1 = *(const bf16x8*)(xs2 + ((c + 1) * 2 + 1) * 512 + lane * 8);
    }
    #pragma unroll
    for (int ct = 0; ct < 8; ++ct) {
      acc[0][ct] = __builtin_amdgcn_mfma_f32_16x16x32_bf16(a0, bcur[ct], acc[0][ct], 0, 0, 0);
      acc[1][ct] = __builtin_amdgcn_mfma_f32_16x16x32_bf16(a1, bcur[ct], acc[1][ct], 0, 0, 0);
    }
    if (c + 1 < NCH) {
      #pragma unroll
      for (int ct = 0; ct < 8; ++ct) bcur[ct] = bnx[ct];
      a0 = na0; a1 = na1;
    }
  }

  // ---- epilogue: dist -> q_unnorm, row sums, normalize ----
  // C/D layout: col = lane&15, row = quad*4 + reg (verified m89/m91)
  float part[2][4];
  #pragma unroll
  for (int rt = 0; rt < 2; ++rt)
    #pragma unroll
    for (int i = 0; i < 4; ++i) part[rt][i] = 0.f;

  #pragma unroll
  for (int rt = 0; rt < 2; ++rt) {
    float xq[4];
    #pragma unroll
    for (int i = 0; i < 4; ++i) xq[i] = xsq_s[rt * 16 + quad * 4 + i];
    #pragma unroll
    for (int ct = 0; ct < 8; ++ct) {
      float wq = wsq_s[col0 + ct * 16 + m16];
      #pragma unroll
      for (int i = 0; i < 4; ++i) {
        float dist = fmaxf(xq[i] + wq - 2.f * acc[rt][ct][i], 0.f);
        float qu = 1.f / (1.f + dist);    // ALPHA=1: (1+dist)^-1 exact
        acc[rt][ct][i] = qu;
        part[rt][i] += qu;
      }
    }
  }
  #pragma unroll
  for (int rt = 0; rt < 2; ++rt)
    #pragma unroll
    for (int i = 0; i < 4; ++i) {
      float s = part[rt][i];
      s += __shfl_xor(s, 1, 64);
      s += __shfl_xor(s, 2, 64);
      s += __shfl_xor(s, 4, 64);
      s += __shfl_xor(s, 8, 64);
      part[rt][i] = s;
    }
  if (m16 == 0) {
    #pragma unroll
    for (int rt = 0; rt < 2; ++rt)
      #pragma unroll
      for (int i = 0; i < 4; ++i)
        red[rt * 16 + quad * 4 + i][wave] = part[rt][i];
  }
  __syncthreads();
  if (tid < ROWS) {
    float t = 0.f;
    #pragma unroll
    for (int w2 = 0; w2 < 8; ++w2) t += red[tid][w2];
    rowtot[tid] = 1.f / t;
  }
  __syncthreads();
  #pragma unroll
  for (int rt = 0; rt < 2; ++rt) {
    #pragma unroll
    for (int i = 0; i < 4; ++i) {
      int r = rt * 16 + quad * 4 + i;
      float inv = rowtot[r];
      float* orow = out + (size_t)(r0 + r) * NCL + col0 + m16;
      #pragma unroll
      for (int ct = 0; ct < 8; ++ct)
        __builtin_nontemporal_store(acc[rt][ct][i] * inv, orow + ct * 16);  // stream, no L2 alloc
    }
  }
}

extern "C" void kernel_launch(void* const* d_in, const int* in_sizes, int n_in,
                              void* d_out, int out_size, void* d_ws, size_t ws_size,
                              hipStream_t stream) {
  const float* x = (const float*)d_in[0];   // [8192][512] fp32
  const float* w = (const float*)d_in[1];   // [1024][512] fp32
  __hip_bfloat16* wck = (__hip_bfloat16*)d_ws;                      // 16*1024*32*2 = 1 MB
  float* wsq = (float*)((char*)d_ws + (size_t)NCH * NCL * BK * 2);  // +4 KB
  float* out = (float*)d_out;

  hipLaunchKernelGGL(prep_w, dim3(NCL / 4), dim3(256), 0, stream, w, wck, wsq);
  hipLaunchKernelGGL(fused, dim3(BATCH / ROWS), dim3(512), 0, stream, x, wck, wsq, out);
}

// Round 4
// 97.678 us; speedup vs baseline: 1.1258x; 1.1258x over previous
//
#include <hip/hip_runtime.h>
#include <hip/hip_bf16.h>

#define BATCH 8192
#define DIM   512
#define NCL   1024
#define ROWS  32
#define BK    32
#define NCH   (DIM / BK)   // 16 chunks of 32 along D
#define NWAVE 16           // 1024 threads

typedef __bf16 bf16x8 __attribute__((ext_vector_type(8)));
typedef float  f32x4  __attribute__((ext_vector_type(4)));

__device__ __forceinline__ unsigned short f2bf(float f) {
  union { float f; unsigned u; } v; v.f = f;
  unsigned r = v.u + 0x7fffu + ((v.u >> 16) & 1u);   // RNE, inputs finite
  return (unsigned short)(r >> 16);
}
__device__ __forceinline__ unsigned pk(float a, float b) {
  return (unsigned)f2bf(a) | ((unsigned)f2bf(b) << 16);
}

// weight [1024][512] fp32 -> chunk-major bf16 wck[16][1024][32], plus wsq[1024].
__global__ __launch_bounds__(256) void prep_w(const float* __restrict__ w,
                                              __hip_bfloat16* __restrict__ wck,
                                              float* __restrict__ wsq) {
  int k    = blockIdx.x * 4 + (threadIdx.x >> 6);
  int lane = threadIdx.x & 63;
  const float4* wrow = (const float4*)(w + (size_t)k * DIM);
  float4 a = wrow[lane * 2 + 0];
  float4 b = wrow[lane * 2 + 1];
  float s = a.x*a.x + a.y*a.y + a.z*a.z + a.w*a.w
          + b.x*b.x + b.y*b.y + b.z*b.z + b.w*b.w;
  #pragma unroll
  for (int m = 32; m >= 1; m >>= 1) s += __shfl_xor(s, m, 64);
  if (lane == 0) wsq[k] = s;
  int c = lane >> 2;
  int j = (lane & 3) * 8;
  uint4 p = { pk(a.x, a.y), pk(a.z, a.w), pk(b.x, b.y), pk(b.z, b.w) };
  *(uint4*)(wck + ((size_t)c * NCL + k) * BK + j) = p;
}

// Fused: 32 rows x 1024 cols per block, 1024 threads = 16 waves (each: 64-col strip,
// 2x4 tiles of 16x16). 256 blocks = 1/CU but 4 waves/SIMD (vs 2 before) — the R3
// profile showed latency-bound at Occupancy 17%; this doubles TLP at equal B-traffic.
__global__ __launch_bounds__(1024, 4) void fused(const float* __restrict__ x,
                                                 const __hip_bfloat16* __restrict__ wck,
                                                 const float* __restrict__ wsq,
                                                 float* __restrict__ out) {
  // xs2[c][rt][lane*8+j]: MFMA A-fragment layout, tile (c,rt) = 512 elems (1 KB)
  __shared__ __align__(16) __hip_bfloat16 xs2[NCH * 2 * 512];   // 32 KB
  __shared__ float wsq_s[NCL];                                  // 4 KB
  __shared__ float xqp[NWAVE][33];                              // x-sumsq partials
  __shared__ float xsq_s[ROWS];
  __shared__ float red[ROWS][NWAVE + 1];
  __shared__ float rowtot[ROWS];

  const int tid = threadIdx.x;
  const int r0  = blockIdx.x * ROWS;

  const int wave = tid >> 6;
  const int lane = tid & 63;
  const int m16  = lane & 15;
  const int quad = lane >> 4;
  const int col0 = wave * 64;          // 64-col strip per wave

  // ---- prologue: chunk-0 B loads issued before staging (L2 latency hidden) ----
  bf16x8 bcur[4];
  {
    const __hip_bfloat16* wp0 = wck + (size_t)(col0 + m16) * BK + quad * 8;
    #pragma unroll
    for (int ct = 0; ct < 4; ++ct)
      bcur[ct] = *(const bf16x8*)(wp0 + ct * (16 * BK));
  }

  // ---- stage x fp32->bf16 into A-frag layout + per-row sumsq partials ----
  {
    int row = tid & 31;                // 0..31
    int seg = tid >> 5;                // 0..31, 16 consecutive d each
    int c = seg >> 1, h = seg & 1;     // chunk, half-of-chunk
    int rt = row >> 4, m = row & 15;
    const float4* src = (const float4*)(x + (size_t)(r0 + row) * DIM + seg * 16);
    float4 v0 = src[0], v1 = src[1], v2 = src[2], v3 = src[3];
    float ss = v0.x*v0.x + v0.y*v0.y + v0.z*v0.z + v0.w*v0.w
             + v1.x*v1.x + v1.y*v1.y + v1.z*v1.z + v1.w*v1.w
             + v2.x*v2.x + v2.y*v2.y + v2.z*v2.z + v2.w*v2.w
             + v3.x*v3.x + v3.y*v3.y + v3.z*v3.z + v3.w*v3.w;
    __hip_bfloat16* base = xs2 + (c * 2 + rt) * 512 + m * 8;
    uint4 p0 = { pk(v0.x, v0.y), pk(v0.z, v0.w), pk(v1.x, v1.y), pk(v1.z, v1.w) };
    uint4 p1 = { pk(v2.x, v2.y), pk(v2.z, v2.w), pk(v3.x, v3.y), pk(v3.z, v3.w) };
    *(uint4*)(base + (h * 2 + 0) * 128) = p0;   // quad h*2,   j=0..7
    *(uint4*)(base + (h * 2 + 1) * 128) = p1;   // quad h*2+1, j=0..7
    ss += __shfl_xor(ss, 32, 64);               // combine the wave's 2 segs of this row
    if (lane < 32) xqp[wave][row] = ss;
    wsq_s[tid] = wsq[tid];
  }

  f32x4 acc[2][4];
  #pragma unroll
  for (int rt = 0; rt < 2; ++rt)
    #pragma unroll
    for (int ct = 0; ct < 4; ++ct)
      acc[rt][ct] = (f32x4){0.f, 0.f, 0.f, 0.f};

  __syncthreads();                     // xs2 / wsq_s / xqp visible
  if (tid < ROWS) {
    float t = 0.f;
    #pragma unroll
    for (int w2 = 0; w2 < NWAVE; ++w2) t += xqp[w2][tid];
    xsq_s[tid] = t;
  }
  __syncthreads();                     // xsq_s visible (cheap, once)

  bf16x8 a0 = *(const bf16x8*)(xs2 + 0 * 512 + lane * 8);
  bf16x8 a1 = *(const bf16x8*)(xs2 + 1 * 512 + lane * 8);

  // ---- K-loop: register double-buffer, prefetch c+1 while MFMA on c ----
  #pragma unroll
  for (int c = 0; c < NCH; ++c) {
    bf16x8 bnx[4], na0, na1;
    if (c + 1 < NCH) {
      const __hip_bfloat16* wp = wck + ((size_t)(c + 1) * NCL + col0 + m16) * BK + quad * 8;
      #pragma unroll
      for (int ct = 0; ct < 4; ++ct)
        bnx[ct] = *(const bf16x8*)(wp + ct * (16 * BK));
      na0 = *(const bf16x8*)(xs2 + ((c + 1) * 2 + 0) * 512 + lane * 8);
      na1 = *(const bf16x8*)(xs2 + ((c + 1) * 2 + 1) * 512 + lane * 8);
    }
    #pragma unroll
    for (int ct = 0; ct < 4; ++ct) {
      acc[0][ct] = __builtin_amdgcn_mfma_f32_16x16x32_bf16(a0, bcur[ct], acc[0][ct], 0, 0, 0);
      acc[1][ct] = __builtin_amdgcn_mfma_f32_16x16x32_bf16(a1, bcur[ct], acc[1][ct], 0, 0, 0);
    }
    if (c + 1 < NCH) {
      #pragma unroll
      for (int ct = 0; ct < 4; ++ct) bcur[ct] = bnx[ct];
      a0 = na0; a1 = na1;
    }
  }

  // ---- epilogue: dist -> q_unnorm, row sums, normalize ----
  // C/D layout: col = lane&15, row = quad*4 + reg (verified m89/m91)
  float part[2][4];
  #pragma unroll
  for (int rt = 0; rt < 2; ++rt)
    #pragma unroll
    for (int i = 0; i < 4; ++i) part[rt][i] = 0.f;

  #pragma unroll
  for (int rt = 0; rt < 2; ++rt) {
    float xq[4];
    #pragma unroll
    for (int i = 0; i < 4; ++i) xq[i] = xsq_s[rt * 16 + quad * 4 + i];
    #pragma unroll
    for (int ct = 0; ct < 4; ++ct) {
      float wq = wsq_s[col0 + ct * 16 + m16];
      #pragma unroll
      for (int i = 0; i < 4; ++i) {
        float dist = fmaxf(xq[i] + wq - 2.f * acc[rt][ct][i], 0.f);
        float qu = 1.f / (1.f + dist);    // ALPHA=1: (1+dist)^-1 exact
        acc[rt][ct][i] = qu;
        part[rt][i] += qu;
      }
    }
  }
  #pragma unroll
  for (int rt = 0; rt < 2; ++rt)
    #pragma unroll
    for (int i = 0; i < 4; ++i) {
      float s = part[rt][i];
      s += __shfl_xor(s, 1, 64);
      s += __shfl_xor(s, 2, 64);
      s += __shfl_xor(s, 4, 64);
      s += __shfl_xor(s, 8, 64);
      part[rt][i] = s;
    }
  if (m16 == 0) {
    #pragma unroll
    for (int rt = 0; rt < 2; ++rt)
      #pragma unroll
      for (int i = 0; i < 4; ++i)
        red[rt * 16 + quad * 4 + i][wave] = part[rt][i];
  }
  __syncthreads();
  if (tid < ROWS) {
    float t = 0.f;
    #pragma unroll
    for (int w2 = 0; w2 < NWAVE; ++w2) t += red[tid][w2];
    rowtot[tid] = 1.f / t;
  }
  __syncthreads();
  #pragma unroll
  for (int rt = 0; rt < 2; ++rt) {
    #pragma unroll
    for (int i = 0; i < 4; ++i) {
      int r = rt * 16 + quad * 4 + i;
      float inv = rowtot[r];
      float* orow = out + (size_t)(r0 + r) * NCL + col0 + m16;
      #pragma unroll
      for (int ct = 0; ct < 4; ++ct)
        orow[ct * 16] = acc[rt][ct][i] * inv;   // normal stores: L2 merges lines
    }
  }
}

extern "C" void kernel_launch(void* const* d_in, const int* in_sizes, int n_in,
                              void* d_out, int out_size, void* d_ws, size_t ws_size,
                              hipStream_t stream) {
  const float* x = (const float*)d_in[0];   // [8192][512] fp32
  const float* w = (const float*)d_in[1];   // [1024][512] fp32
  __hip_bfloat16* wck = (__hip_bfloat16*)d_ws;                      // 1 MB
  float* wsq = (float*)((char*)d_ws + (size_t)NCH * NCL * BK * 2);  // +4 KB
  float* out = (float*)d_out;

  hipLaunchKernelGGL(prep_w, dim3(NCL / 4), dim3(256), 0, stream, w, wck, wsq);
  hipLaunchKernelGGL(fused, dim3(BATCH / ROWS), dim3(1024), 0, stream, x, wck, wsq, out);
}